// Round 1
// baseline (323.910 us; speedup 1.0000x reference)
//
#include <hip/hip_runtime.h>

#define NPTS 2048
#define TPB  256
#define EPT  8   // elements per thread: 256*8 = 2048

// One block per batch row. State lives in LDS (double-buffered); 500 steps
// in a single kernel, one barrier per step, one coalesced 8KB store per step.
__global__ __launch_bounds__(TPB) void lxf_persist(
    const float* __restrict__ init, float* __restrict__ out,
    int nbatch, int nsteps)
{
    __shared__ float ub[2][NPTS];
    __shared__ float ledge[2][TPB];   // first element of each thread's chunk
    __shared__ float redge[2][TPB];   // last  element of each thread's chunk

    const int b   = blockIdx.x;
    const int tid = threadIdx.x;
    const size_t rowoff = (size_t)b * NPTS;
    const float lam = (float)(5.0e-4 / (10.0 / 2048.0));   // DT/DX = 0.1024

    // ---- load init row (2x float4 per thread), seed LDS buf 0, write t=0 ----
    const float4* src = reinterpret_cast<const float4*>(init + rowoff);
    float4 v0 = src[2 * tid];
    float4 v1 = src[2 * tid + 1];

    {
        float4* l0 = reinterpret_cast<float4*>(ub[0]);
        l0[2 * tid]     = v0;
        l0[2 * tid + 1] = v1;
        ledge[0][tid] = v0.x;
        redge[0][tid] = v1.w;
        float4* dst = reinterpret_cast<float4*>(out + rowoff);
        dst[2 * tid]     = v0;
        dst[2 * tid + 1] = v1;
    }
    __syncthreads();

    const size_t stride_t = (size_t)nbatch * NPTS;
    int cur = 0;

    for (int t = 1; t < nsteps; ++t) {
        // x[k] = u[base-1+k], k=0..9, base = tid*EPT  (edges clamped)
        float x[10];
        const float4* l = reinterpret_cast<const float4*>(ub[cur]);
        float4 a0 = l[2 * tid];
        float4 a1 = l[2 * tid + 1];
        x[1] = a0.x; x[2] = a0.y; x[3] = a0.z; x[4] = a0.w;
        x[5] = a1.x; x[6] = a1.y; x[7] = a1.z; x[8] = a1.w;
        x[0] = (tid == 0)       ? a0.x : redge[cur][tid - 1];
        x[9] = (tid == TPB - 1) ? a1.w : ledge[cur][tid + 1];

        // g = 0.5*f(u) = u*(0.75 + u*(9.375 + u*(-25.25 + u*(18.75 - 3.125*u^2))))
        // p = f'(u)    = 1.5 + u*(37.5 + u*(-151.5 + u*(150 - 37.5*u^2)))
        float g[10], p[10];
        #pragma unroll
        for (int k = 0; k < 10; ++k) {
            const float u  = x[k];
            const float u2 = u * u;
            float gg = fmaf(u2, -3.125f, 18.75f);
            gg = fmaf(u, gg, -25.25f);
            gg = fmaf(u, gg, 9.375f);
            gg = fmaf(u, gg, 0.75f);
            g[k] = u * gg;
            float pp = fmaf(u2, -37.5f, 150.0f);
            pp = fmaf(u, pp, -151.5f);
            pp = fmaf(u, pp, 37.5f);
            p[k] = fmaf(u, pp, 1.5f);
        }

        // f_half[j] = (g[j]+g[j+1]) - 0.5*max(|p_j|,|p_j+1|)*(x[j+1]-x[j])
        float fh[9];
        #pragma unroll
        for (int j = 0; j < 9; ++j) {
            const float alpha = fmaxf(fabsf(p[j]), fabsf(p[j + 1]));
            fh[j] = fmaf(-0.5f * alpha, x[j + 1] - x[j], g[j] + g[j + 1]);
        }

        // u_new[p] = u[p] - lam*(fh[p] - fh[p-1])
        float un[8];
        #pragma unroll
        for (int m = 0; m < 8; ++m)
            un[m] = fmaf(-lam, fh[m + 1] - fh[m], x[m + 1]);

        if (tid == 0)       un[0] = un[1];   // u[0]   = u[1]
        if (tid == TPB - 1) un[7] = un[6];   // u[N-1] = u[N-2]

        const int nxt = cur ^ 1;
        const float4 w0 = make_float4(un[0], un[1], un[2], un[3]);
        const float4 w1 = make_float4(un[4], un[5], un[6], un[7]);

        float4* ln = reinterpret_cast<float4*>(ub[nxt]);
        ln[2 * tid]     = w0;
        ln[2 * tid + 1] = w1;
        ledge[nxt][tid] = un[0];
        redge[nxt][tid] = un[7];

        float4* dst = reinterpret_cast<float4*>(out + (size_t)t * stride_t + rowoff);
        dst[2 * tid]     = w0;
        dst[2 * tid + 1] = w1;

        cur = nxt;
        __syncthreads();
    }
}

extern "C" void kernel_launch(void* const* d_in, const int* in_sizes, int n_in,
                              void* d_out, int out_size, void* d_ws, size_t ws_size,
                              hipStream_t stream) {
    const float* init = (const float*)d_in[0];
    float* out = (float*)d_out;

    const int nbatch = in_sizes[0] / NPTS;            // 128
    const int nsteps = out_size / in_sizes[0];        // 500

    hipLaunchKernelGGL(lxf_persist, dim3(nbatch), dim3(TPB), 0, stream,
                       init, out, nbatch, nsteps);
}

// Round 4
// 218.113 us; speedup vs baseline: 1.4851x; 1.4851x over previous
//
#include <hip/hip_runtime.h>

#define NPTS 2048
#define TPB  256
// 8 elements per thread, register-resident across all timesteps.

typedef float v4f __attribute__((ext_vector_type(4)));   // clang-native float4

// Barrier WITHOUT the vmcnt(0) drain __syncthreads() would emit:
// LDS writes must be visible (lgkmcnt), but global stores may stay in flight.
#define EDGE_BARRIER() do {                                   \
    asm volatile("s_waitcnt lgkmcnt(0)" ::: "memory");        \
    __builtin_amdgcn_s_barrier();                             \
    asm volatile("" ::: "memory");                            \
} while (0)

__global__ __launch_bounds__(TPB) void lxf_persist(
    const float* __restrict__ init, float* __restrict__ out,
    int nbatch, int nsteps)
{
    // Only halo values cross threads; double-buffered, one barrier per step.
    __shared__ float ledge[2][TPB];   // first element of each thread's chunk
    __shared__ float redge[2][TPB];   // last  element of each thread's chunk

    const int b   = blockIdx.x;
    const int tid = threadIdx.x;
    const size_t rowoff = (size_t)b * NPTS;
    const float lam = (float)(5.0e-4 / (10.0 / 2048.0));   // DT/DX = 0.1024

    // ---- load init row (2x 16B), write t=0, seed edge buffers ----
    const v4f* src = reinterpret_cast<const v4f*>(init + rowoff);
    v4f a0 = src[2 * tid];
    v4f a1 = src[2 * tid + 1];

    float s[8];
    s[0] = a0.x; s[1] = a0.y; s[2] = a0.z; s[3] = a0.w;
    s[4] = a1.x; s[5] = a1.y; s[6] = a1.z; s[7] = a1.w;

    {
        v4f* dst0 = reinterpret_cast<v4f*>(out + rowoff);
        __builtin_nontemporal_store(a0, &dst0[2 * tid]);
        __builtin_nontemporal_store(a1, &dst0[2 * tid + 1]);
        ledge[0][tid] = s[0];
        redge[0][tid] = s[7];
    }
    EDGE_BARRIER();

    const size_t stride_t  = (size_t)nbatch * NPTS;       // floats per step
    const size_t stride_t4 = stride_t / 4;                // v4fs per step
    const int tl = (tid == 0)       ? 0       : tid - 1;  // clamped neighbor idx
    const int tr = (tid == TPB - 1) ? TPB - 1 : tid + 1;

    v4f* dstw = reinterpret_cast<v4f*>(out + rowoff);
    int cur = 0;

    for (int t = 1; t < nsteps; ++t) {
        dstw += stride_t4;

        // x[k] = u[tid*8 - 1 + k], k=0..9 (edges clamped)
        float x[10];
        #pragma unroll
        for (int m = 0; m < 8; ++m) x[m + 1] = s[m];
        const float xl = redge[cur][tl];
        const float xr = ledge[cur][tr];
        x[0] = (tid == 0)       ? x[1] : xl;
        x[9] = (tid == TPB - 1) ? x[8] : xr;

        // g = 0.5*f(u) = u*(0.75 + u*(9.375 + u*(-25.25 + u*(18.75 - 3.125 u^2))))
        // p = f'(u)    = 1.5 + u*(37.5 + u*(-151.5 + u*(150 - 37.5 u^2)))
        float g[10], p[10];
        #pragma unroll
        for (int k = 0; k < 10; ++k) {
            const float u  = x[k];
            const float u2 = u * u;
            float gg = fmaf(u2, -3.125f, 18.75f);
            gg = fmaf(u, gg, -25.25f);
            gg = fmaf(u, gg, 9.375f);
            gg = fmaf(u, gg, 0.75f);
            g[k] = u * gg;
            float pp = fmaf(u2, -37.5f, 150.0f);
            pp = fmaf(u, pp, -151.5f);
            pp = fmaf(u, pp, 37.5f);
            p[k] = fmaf(u, pp, 1.5f);
        }

        // f_half[j] = (g[j]+g[j+1]) - 0.5*max(|p_j|,|p_{j+1}|)*(x[j+1]-x[j])
        float fh[9];
        #pragma unroll
        for (int j = 0; j < 9; ++j) {
            const float alpha = fmaxf(fabsf(p[j]), fabsf(p[j + 1]));
            fh[j] = fmaf(-0.5f * alpha, x[j + 1] - x[j], g[j] + g[j + 1]);
        }

        // u_new[m] = u[m] - lam*(fh[m+1] - fh[m])
        float un[8];
        #pragma unroll
        for (int m = 0; m < 8; ++m)
            un[m] = fmaf(-lam, fh[m + 1] - fh[m], x[m + 1]);

        if (tid == 0)       un[0] = un[1];   // u[0]   = u[1]
        if (tid == TPB - 1) un[7] = un[6];   // u[N-1] = u[N-2]

        // publish halos for next step (other buffer), then stream the row out
        const int nxt = cur ^ 1;
        ledge[nxt][tid] = un[0];
        redge[nxt][tid] = un[7];

        v4f w0, w1;
        w0.x = un[0]; w0.y = un[1]; w0.z = un[2]; w0.w = un[3];
        w1.x = un[4]; w1.y = un[5]; w1.z = un[6]; w1.w = un[7];
        __builtin_nontemporal_store(w0, &dstw[2 * tid]);
        __builtin_nontemporal_store(w1, &dstw[2 * tid + 1]);

        #pragma unroll
        for (int m = 0; m < 8; ++m) s[m] = un[m];

        cur = nxt;
        EDGE_BARRIER();
    }
}

extern "C" void kernel_launch(void* const* d_in, const int* in_sizes, int n_in,
                              void* d_out, int out_size, void* d_ws, size_t ws_size,
                              hipStream_t stream) {
    const float* init = (const float*)d_in[0];
    float* out = (float*)d_out;

    const int nbatch = in_sizes[0] / NPTS;       // 128
    const int nsteps = out_size / in_sizes[0];   // 500

    hipLaunchKernelGGL(lxf_persist, dim3(nbatch), dim3(TPB), 0, stream,
                       init, out, nbatch, nsteps);
}

// Round 5
// 200.552 us; speedup vs baseline: 1.6151x; 1.0876x over previous
//
#include <hip/hip_runtime.h>

#define NPTS 2048
#define TPB  512
#define EPT  4    // 512 threads x 4 elems = 2048; 8 waves/block = 2 waves/SIMD

typedef float  v4f __attribute__((ext_vector_type(4)));
typedef float  v2f __attribute__((ext_vector_type(2)));

// Barrier WITHOUT the vmcnt(0) drain __syncthreads() would emit:
// LDS writes must be visible (lgkmcnt), but global stores may stay in flight.
#define EDGE_BARRIER() do {                                   \
    asm volatile("s_waitcnt lgkmcnt(0)" ::: "memory");        \
    __builtin_amdgcn_s_barrier();                             \
    asm volatile("" ::: "memory");                            \
} while (0)

__global__ __launch_bounds__(TPB) void lxf_persist(
    const float* __restrict__ init, float* __restrict__ out,
    int nbatch, int nsteps)
{
    // Per-thread halo pair: e[buf][tid] = {first elem, last elem} of chunk.
    __shared__ v2f e[2][TPB];

    const int b   = blockIdx.x;
    const int tid = threadIdx.x;
    const size_t rowoff = (size_t)b * NPTS;
    const float lam = (float)(5.0e-4 / (10.0 / 2048.0));   // DT/DX = 0.1024

    // ---- load init chunk (16B), write t=0, seed edge buffer ----
    const v4f* src = reinterpret_cast<const v4f*>(init + rowoff);
    v4f a0 = src[tid];

    float s[4];
    s[0] = a0.x; s[1] = a0.y; s[2] = a0.z; s[3] = a0.w;

    {
        v4f* dst0 = reinterpret_cast<v4f*>(out + rowoff);
        __builtin_nontemporal_store(a0, &dst0[tid]);
        v2f e0; e0.x = s[0]; e0.y = s[3];
        e[0][tid] = e0;
    }
    EDGE_BARRIER();

    const size_t stride_t4 = ((size_t)nbatch * NPTS) / 4;  // v4fs per step
    const int tl = (tid == 0)       ? 0       : tid - 1;   // clamped neighbors
    const int tr = (tid == TPB - 1) ? TPB - 1 : tid + 1;

    v4f* dstw = reinterpret_cast<v4f*>(out + rowoff);
    int cur = 0;

    for (int t = 1; t < nsteps; ++t) {
        dstw += stride_t4;

        // x[k] = u[tid*4 - 1 + k], k=0..5 (row edges clamped)
        float x[6];
        #pragma unroll
        for (int m = 0; m < 4; ++m) x[m + 1] = s[m];
        const float xl = e[cur][tl].y;   // last elem of left neighbor
        const float xr = e[cur][tr].x;   // first elem of right neighbor
        x[0] = (tid == 0)       ? x[1] : xl;
        x[5] = (tid == TPB - 1) ? x[4] : xr;

        // g = 0.5*f(u) = u*(0.75 + u*(9.375 + u*(-25.25 + u*(18.75 - 3.125 u^2))))
        // p = f'(u)    = 1.5 + u*(37.5 + u*(-151.5 + u*(150 - 37.5 u^2)))
        float g[6], p[6];
        #pragma unroll
        for (int k = 0; k < 6; ++k) {
            const float u  = x[k];
            const float u2 = u * u;
            float gg = fmaf(u2, -3.125f, 18.75f);
            gg = fmaf(u, gg, -25.25f);
            gg = fmaf(u, gg, 9.375f);
            gg = fmaf(u, gg, 0.75f);
            g[k] = u * gg;
            float pp = fmaf(u2, -37.5f, 150.0f);
            pp = fmaf(u, pp, -151.5f);
            pp = fmaf(u, pp, 37.5f);
            p[k] = fmaf(u, pp, 1.5f);
        }

        // f_half[j] = (g[j]+g[j+1]) - 0.5*max(|p_j|,|p_{j+1}|)*(x[j+1]-x[j])
        float fh[5];
        #pragma unroll
        for (int j = 0; j < 5; ++j) {
            const float alpha = fmaxf(fabsf(p[j]), fabsf(p[j + 1]));
            fh[j] = fmaf(-0.5f * alpha, x[j + 1] - x[j], g[j] + g[j + 1]);
        }

        // u_new[m] = u[m] - lam*(fh[m+1] - fh[m])
        float un[4];
        #pragma unroll
        for (int m = 0; m < 4; ++m)
            un[m] = fmaf(-lam, fh[m + 1] - fh[m], x[m + 1]);

        if (tid == 0)       un[0] = un[1];   // u[0]   = u[1]
        if (tid == TPB - 1) un[3] = un[2];   // u[N-1] = u[N-2]

        // publish halos for next step (other buffer), then stream the row out
        const int nxt = cur ^ 1;
        v2f en; en.x = un[0]; en.y = un[3];
        e[nxt][tid] = en;

        v4f w0;
        w0.x = un[0]; w0.y = un[1]; w0.z = un[2]; w0.w = un[3];
        __builtin_nontemporal_store(w0, &dstw[tid]);

        #pragma unroll
        for (int m = 0; m < 4; ++m) s[m] = un[m];

        cur = nxt;
        EDGE_BARRIER();
    }
}

extern "C" void kernel_launch(void* const* d_in, const int* in_sizes, int n_in,
                              void* d_out, int out_size, void* d_ws, size_t ws_size,
                              hipStream_t stream) {
    const float* init = (const float*)d_in[0];
    float* out = (float*)d_out;

    const int nbatch = in_sizes[0] / NPTS;       // 128
    const int nsteps = out_size / in_sizes[0];   // 500

    hipLaunchKernelGGL(lxf_persist, dim3(nbatch), dim3(TPB), 0, stream,
                       init, out, nbatch, nsteps);
}

// Round 6
// 190.571 us; speedup vs baseline: 1.6997x; 1.0524x over previous
//
#include <hip/hip_runtime.h>

#define NPTS 2048
#define TPB  512   // 4 elems/thread; 8 waves/block = 2 waves/SIMD

typedef float v4f __attribute__((ext_vector_type(4)));
typedef float v2f __attribute__((ext_vector_type(2)));

// Barrier WITHOUT the vmcnt(0) drain __syncthreads() would emit:
// LDS writes must be visible (lgkmcnt), global stores may stay in flight.
#define EDGE_BARRIER() do {                                   \
    asm volatile("s_waitcnt lgkmcnt(0)" ::: "memory");        \
    __builtin_amdgcn_s_barrier();                             \
    asm volatile("" ::: "memory");                            \
} while (0)

__global__ __launch_bounds__(TPB) void lxf_persist(
    const float* __restrict__ init, float* __restrict__ out,
    int nbatch, int nsteps)
{
    // Per-thread halo pair: e[buf][tid] = {first elem, last elem} of chunk.
    __shared__ v2f e[2][TPB];

    const int b   = blockIdx.x;
    const int tid = threadIdx.x;
    const size_t rowoff = (size_t)b * NPTS;
    const float lam = (float)(5.0e-4 / (10.0 / 2048.0));   // DT/DX = 0.1024

    // ---- load init chunk (16B), write t=0, seed edge buffer ----
    const v4f* src = reinterpret_cast<const v4f*>(init + rowoff);
    v4f a0 = src[tid];
    float s0 = a0.x, s1 = a0.y, s2 = a0.z, s3 = a0.w;

    {
        v4f* dst0 = reinterpret_cast<v4f*>(out + rowoff);
        dst0[tid] = a0;                    // plain store (L2-accept retire)
        v2f e0; e0.x = s0; e0.y = s3;
        e[0][tid] = e0;
    }
    EDGE_BARRIER();

    const size_t stride_t4 = ((size_t)nbatch * NPTS) / 4;  // v4fs per step
    const int tl = (tid == 0)       ? 0       : tid - 1;   // clamped neighbors
    const int tr = (tid == TPB - 1) ? TPB - 1 : tid + 1;

    v4f* dstw = reinterpret_cast<v4f*>(out + rowoff);

// One timestep: read halos from e[CUR], publish new halos to e[NXT].
// Each expansion has its own w_ registers -> unrolled x4 gives 4 stores
// in flight (compiler emits counted vmcnt, not per-step drain).
#define STEP(CUR, NXT) do {                                            \
    dstw += stride_t4;                                                 \
    const v2f el_ = e[CUR][tl];                                        \
    const v2f er_ = e[CUR][tr];                                        \
    float x[6];                                                        \
    x[1] = s0; x[2] = s1; x[3] = s2; x[4] = s3;                        \
    x[0] = (tid == 0)       ? s0 : el_.y;                              \
    x[5] = (tid == TPB - 1) ? s3 : er_.x;                              \
    /* g = 0.5*f(u); p = f'(u) */                                      \
    float g[6], p[6];                                                  \
    _Pragma("unroll")                                                  \
    for (int k = 0; k < 6; ++k) {                                      \
        const float u  = x[k];                                         \
        const float uu = u * u;                                        \
        float gg = fmaf(uu, -3.125f, 18.75f);                          \
        gg = fmaf(u, gg, -25.25f);                                     \
        gg = fmaf(u, gg, 9.375f);                                      \
        gg = fmaf(u, gg, 0.75f);                                       \
        g[k] = u * gg;                                                 \
        float pp = fmaf(uu, -37.5f, 150.0f);                           \
        pp = fmaf(u, pp, -151.5f);                                     \
        pp = fmaf(u, pp, 37.5f);                                       \
        p[k] = fmaf(u, pp, 1.5f);                                      \
    }                                                                  \
    float fh[5];                                                       \
    _Pragma("unroll")                                                  \
    for (int j = 0; j < 5; ++j) {                                      \
        const float alpha = fmaxf(fabsf(p[j]), fabsf(p[j + 1]));       \
        fh[j] = fmaf(-0.5f * alpha, x[j + 1] - x[j], g[j] + g[j + 1]); \
    }                                                                  \
    float u0_ = fmaf(-lam, fh[1] - fh[0], x[1]);                       \
    float u1_ = fmaf(-lam, fh[2] - fh[1], x[2]);                       \
    float u2_ = fmaf(-lam, fh[3] - fh[2], x[3]);                       \
    float u3_ = fmaf(-lam, fh[4] - fh[3], x[4]);                       \
    if (tid == 0)       u0_ = u1_;   /* u[0]   = u[1]   */             \
    if (tid == TPB - 1) u3_ = u2_;   /* u[N-1] = u[N-2] */             \
    v2f en_; en_.x = u0_; en_.y = u3_;                                 \
    e[NXT][tid] = en_;                                                 \
    v4f w_; w_.x = u0_; w_.y = u1_; w_.z = u2_; w_.w = u3_;            \
    dstw[tid] = w_;                  /* plain store, stays in flight */\
    s0 = u0_; s1 = u1_; s2 = u2_; s3 = u3_;                            \
    EDGE_BARRIER();                                                    \
} while (0)

    const int n4 = (nsteps - 1) / 4;            // 124 when nsteps=500
    for (int i = 0; i < n4; ++i) {
        STEP(0, 1);
        STEP(1, 0);
        STEP(0, 1);
        STEP(1, 0);
    }
    const int rem = (nsteps - 1) - 4 * n4;      // 3 when nsteps=500
    if (rem > 0) STEP(0, 1);
    if (rem > 1) STEP(1, 0);
    if (rem > 2) STEP(0, 1);
#undef STEP
}

extern "C" void kernel_launch(void* const* d_in, const int* in_sizes, int n_in,
                              void* d_out, int out_size, void* d_ws, size_t ws_size,
                              hipStream_t stream) {
    const float* init = (const float*)d_in[0];
    float* out = (float*)d_out;

    const int nbatch = in_sizes[0] / NPTS;       // 128
    const int nsteps = out_size / in_sizes[0];   // 500

    hipLaunchKernelGGL(lxf_persist, dim3(nbatch), dim3(TPB), 0, stream,
                       init, out, nbatch, nsteps);
}